// Round 1
// baseline (636.609 us; speedup 1.0000x reference)
//
#include <hip/hip_runtime.h>
#include <hip/hip_bf16.h>

// Relative-position causal attention, B=4 H=16 Q=K=1024 D=64 (fp32 in/out).
// d_out = [output (BH*Q*D) | p_attn (BH*Q*K)] fp32.
// Pipeline: K1 content scores -> K2 rel+softmax (per-q) -> K3 P@V -> K4 P@bigr_v.
// Score GEMMs use split-bf16 (hi+lo, 3 MFMAs) for precision; PV GEMMs single bf16.

#define BH 64
#define SQ 1024
#define SK 1024
#define DH 64
#define SCALE 0.125f

typedef __attribute__((ext_vector_type(4))) float f32x4;
typedef __attribute__((ext_vector_type(8))) unsigned short ushort8;
typedef __attribute__((ext_vector_type(8))) __bf16 bf16x8;

static __device__ inline unsigned short f2bf(float x) {
    unsigned u = __float_as_uint(x);
    unsigned r = u + 0x7FFFu + ((u >> 16) & 1u);
    return (unsigned short)(r >> 16);
}
static __device__ inline float bf2f(unsigned short s) {
    return __uint_as_float(((unsigned)s) << 16);
}

struct Frag2 { bf16x8 h, l; };

// Load 8 contiguous fp32, produce hi/lo bf16 split fragments.
static __device__ inline Frag2 load_split(const float* __restrict__ p) {
    float4 x0 = *reinterpret_cast<const float4*>(p);
    float4 x1 = *reinterpret_cast<const float4*>(p + 4);
    float v[8] = {x0.x, x0.y, x0.z, x0.w, x1.x, x1.y, x1.z, x1.w};
    ushort8 uh, ul;
#pragma unroll
    for (int j = 0; j < 8; ++j) {
        unsigned short h = f2bf(v[j]);
        float r = v[j] - bf2f(h);
        uh[j] = h;
        ul[j] = f2bf(r);
    }
    Frag2 f;
    f.h = __builtin_bit_cast(bf16x8, uh);
    f.l = __builtin_bit_cast(bf16x8, ul);
    return f;
}

// Load 8 contiguous fp32 as single bf16 fragment.
static __device__ inline bf16x8 load_bf8(const float* __restrict__ p) {
    float4 x0 = *reinterpret_cast<const float4*>(p);
    float4 x1 = *reinterpret_cast<const float4*>(p + 4);
    float v[8] = {x0.x, x0.y, x0.z, x0.w, x1.x, x1.y, x1.z, x1.w};
    ushort8 u;
#pragma unroll
    for (int j = 0; j < 8; ++j) u[j] = f2bf(v[j]);
    return __builtin_bit_cast(bf16x8, u);
}

// Load 8 fp32 strided by `stride` floats, single bf16 fragment.
static __device__ inline bf16x8 load_bf8_strided(const float* __restrict__ p, int stride) {
    ushort8 u;
#pragma unroll
    for (int j = 0; j < 8; ++j) u[j] = f2bf(p[(size_t)j * stride]);
    return __builtin_bit_cast(bf16x8, u);
}

#define MFMA(a, b, c) __builtin_amdgcn_mfma_f32_16x16x32_bf16((a), (b), (c), 0, 0, 0)

static __device__ inline f32x4 mfma_split(const Frag2& a, const Frag2& b, f32x4 c) {
    c = MFMA(a.h, b.h, c);
    c = MFMA(a.h, b.l, c);
    c = MFMA(a.l, b.h, c);
    return c;
}

// ---------------- K1: content scores Q@K^T * scale -> P region (zeros above diag)
__global__ __launch_bounds__(256) void k_scores(const float* __restrict__ q,
                                                const float* __restrict__ k,
                                                float* __restrict__ P) {
    const int kt = blockIdx.x, qt = blockIdx.y, bh = blockIdx.z;
    const int tid = threadIdx.x;
    const int kbase = kt * 64;
    if (kbase > qt * 64 + 63) {  // fully masked tile: zeros
        const int row = qt * 64 + (tid >> 2);
        float4 z = {0.f, 0.f, 0.f, 0.f};
        float4* dst = reinterpret_cast<float4*>(
            &P[((size_t)bh * SQ + row) * SK + kbase + (tid & 3) * 16]);
        dst[0] = z; dst[1] = z; dst[2] = z; dst[3] = z;
        return;
    }
    const int w = tid >> 6, l = tid & 63;
    const int lm = l & 15, lg = l >> 4;
    const int q0 = qt * 64 + w * 16;
    const float* qrow = q + ((size_t)bh * SQ + q0 + lm) * DH + lg * 8;
    Frag2 a0 = load_split(qrow);
    Frag2 a1 = load_split(qrow + 32);
#pragma unroll
    for (int nt = 0; nt < 4; ++nt) {
        const int kc = kbase + nt * 16 + lm;
        f32x4 acc = {0.f, 0.f, 0.f, 0.f};
        if (kbase + nt * 16 <= q0 + 15) {  // tile not fully masked for this wave
            const float* krow = k + ((size_t)bh * SK + kc) * DH + lg * 8;
            Frag2 b0 = load_split(krow);
            Frag2 b1 = load_split(krow + 32);
            acc = mfma_split(a0, b0, acc);
            acc = mfma_split(a1, b1, acc);
        }
#pragma unroll
        for (int r = 0; r < 4; ++r) {
            const int qq = q0 + lg * 4 + r;
            float v = (kc <= qq) ? acc[r] * SCALE : 0.f;
            P[((size_t)bh * SQ + qq) * SK + kc] = v;
        }
    }
}

// ---------------- K2: per-q rel term + softmax over k<=q (3 L2-hot sweeps)
__global__ __launch_bounds__(256) void k_rel_softmax(const float* __restrict__ query,
                                                     const float* __restrict__ bigr_k,
                                                     float* __restrict__ P) {
    const int qpos = SQ - 1 - blockIdx.x;  // big blocks first
    const int tid = threadIdx.x;
    const int w = tid >> 6, l = tid & 63;
    const int lm = l & 15, lg = l >> 4;
    const int bh0 = w * 16;
    const int KE = qpos + 1;
    const int ntiles = (KE + 63) >> 6;

    const float* qrow = query + ((size_t)(bh0 + lm) * SQ + qpos) * DH + lg * 8;
    Frag2 a0 = load_split(qrow);
    Frag2 a1 = load_split(qrow + 32);

    float vmax[4] = {-3e38f, -3e38f, -3e38f, -3e38f};
    // sweep 1: rel MFMA + add content, write raw combined, track max
    for (int t = 0; t < ntiles; ++t) {
        const int k0 = t * 64;
#pragma unroll
        for (int nt = 0; nt < 4; ++nt) {
            if (k0 + nt * 16 >= KE) continue;
            const int kc = k0 + nt * 16 + lm;
            const float* brow = bigr_k + ((size_t)qpos * SK + kc) * DH + lg * 8;
            Frag2 b0 = load_split(brow);
            Frag2 b1 = load_split(brow + 32);
            f32x4 acc = {0.f, 0.f, 0.f, 0.f};
            acc = mfma_split(a0, b0, acc);
            acc = mfma_split(a1, b1, acc);
            if (kc < KE) {
#pragma unroll
                for (int r = 0; r < 4; ++r) {
                    const int bh = bh0 + lg * 4 + r;
                    const size_t idx = ((size_t)bh * SQ + qpos) * SK + kc;
                    float s = P[idx] + acc[r] * SCALE;
                    P[idx] = s;
                    vmax[r] = fmaxf(vmax[r], s);
                }
            }
        }
    }
#pragma unroll
    for (int r = 0; r < 4; ++r) {
        float m = vmax[r];
        for (int s = 1; s < 16; s <<= 1) m = fmaxf(m, __shfl_xor(m, s));
        vmax[r] = m;
    }
    // sweep 2: exp(s - max), accumulate row sum, write e
    float lsum[4] = {0.f, 0.f, 0.f, 0.f};
    for (int t = 0; t < ntiles; ++t) {
        const int k0 = t * 64;
#pragma unroll
        for (int nt = 0; nt < 4; ++nt) {
            const int kc = k0 + nt * 16 + lm;
            if (kc < KE) {
#pragma unroll
                for (int r = 0; r < 4; ++r) {
                    const int bh = bh0 + lg * 4 + r;
                    const size_t idx = ((size_t)bh * SQ + qpos) * SK + kc;
                    float e = __expf(P[idx] - vmax[r]);
                    P[idx] = e;
                    lsum[r] += e;
                }
            }
        }
    }
#pragma unroll
    for (int r = 0; r < 4; ++r) {
        float s = lsum[r];
        for (int m = 1; m < 16; m <<= 1) s += __shfl_xor(s, m);
        lsum[r] = 1.0f / s;
    }
    // sweep 3: normalize
    for (int t = 0; t < ntiles; ++t) {
        const int k0 = t * 64;
#pragma unroll
        for (int nt = 0; nt < 4; ++nt) {
            const int kc = k0 + nt * 16 + lm;
            if (kc < KE) {
#pragma unroll
                for (int r = 0; r < 4; ++r) {
                    const int bh = bh0 + lg * 4 + r;
                    const size_t idx = ((size_t)bh * SQ + qpos) * SK + kc;
                    P[idx] *= lsum[r];
                }
            }
        }
    }
}

// ---------------- K3: out = P @ V (per bh, q-tiles of 64)
__global__ __launch_bounds__(256) void k_pv(const float* __restrict__ P,
                                            const float* __restrict__ V,
                                            float* __restrict__ out) {
    const int qt = blockIdx.x, bh = blockIdx.y;
    const int tid = threadIdx.x;
    const int w = tid >> 6, l = tid & 63;
    const int lm = l & 15, lg = l >> 4;
    const int q0 = qt * 64 + w * 16;
    f32x4 acc[4] = {{0.f,0.f,0.f,0.f},{0.f,0.f,0.f,0.f},{0.f,0.f,0.f,0.f},{0.f,0.f,0.f,0.f}};
    const int kend = q0 + 16;  // covers k <= q0+15; P has zeros beyond row's q
    for (int k0 = 0; k0 < kend; k0 += 32) {
        const float* arow = P + ((size_t)bh * SQ + q0 + lm) * SK + k0 + lg * 8;
        bf16x8 a = load_bf8(arow);
#pragma unroll
        for (int nt = 0; nt < 4; ++nt) {
            const float* bcol = V + ((size_t)bh * SK + k0 + lg * 8) * DH + nt * 16 + lm;
            bf16x8 b = load_bf8_strided(bcol, DH);
            acc[nt] = MFMA(a, b, acc[nt]);
        }
    }
#pragma unroll
    for (int nt = 0; nt < 4; ++nt)
#pragma unroll
        for (int r = 0; r < 4; ++r)
            out[((size_t)bh * SQ + q0 + lg * 4 + r) * DH + nt * 16 + lm] = acc[nt][r];
}

// ---------------- K4: out += P @ bigr_v[q] (per q, all bh)
__global__ __launch_bounds__(256) void k_pr(const float* __restrict__ P,
                                            const float* __restrict__ bigr_v,
                                            float* __restrict__ out) {
    const int qpos = SQ - 1 - blockIdx.x;  // big blocks first
    const int tid = threadIdx.x;
    const int w = tid >> 6, l = tid & 63;
    const int lm = l & 15, lg = l >> 4;
    const int bh0 = w * 16;
    f32x4 acc[4] = {{0.f,0.f,0.f,0.f},{0.f,0.f,0.f,0.f},{0.f,0.f,0.f,0.f},{0.f,0.f,0.f,0.f}};
    const int kend = qpos + 1;
    for (int k0 = 0; k0 < kend; k0 += 32) {
        const float* arow = P + ((size_t)(bh0 + lm) * SQ + qpos) * SK + k0 + lg * 8;
        bf16x8 a = load_bf8(arow);
#pragma unroll
        for (int nt = 0; nt < 4; ++nt) {
            const float* bcol = bigr_v + ((size_t)qpos * SK + k0 + lg * 8) * DH + nt * 16 + lm;
            bf16x8 b = load_bf8_strided(bcol, DH);
            acc[nt] = MFMA(a, b, acc[nt]);
        }
    }
#pragma unroll
    for (int nt = 0; nt < 4; ++nt)
#pragma unroll
        for (int r = 0; r < 4; ++r) {
            const size_t o = ((size_t)(bh0 + lg * 4 + r) * SQ + qpos) * DH + nt * 16 + lm;
            out[o] += acc[nt][r];
        }
}

extern "C" void kernel_launch(void* const* d_in, const int* in_sizes, int n_in,
                              void* d_out, int out_size, void* d_ws, size_t ws_size,
                              hipStream_t stream) {
    const float* query  = (const float*)d_in[0];
    const float* key    = (const float*)d_in[1];
    const float* value  = (const float*)d_in[2];
    const float* bigr_k = (const float*)d_in[3];
    const float* bigr_v = (const float*)d_in[4];
    float* out = (float*)d_out;                       // BH*SQ*DH
    float* P   = out + (size_t)BH * SQ * DH;          // BH*SQ*SK

    k_scores<<<dim3(16, 16, BH), 256, 0, stream>>>(query, key, P);
    k_rel_softmax<<<dim3(SQ), 256, 0, stream>>>(query, bigr_k, P);
    k_pv<<<dim3(16, BH), 256, 0, stream>>>(P, value, out);
    k_pr<<<dim3(SQ), 256, 0, stream>>>(P, bigr_v, out);
}

// Round 2
// 598.375 us; speedup vs baseline: 1.0639x; 1.0639x over previous
//
#include <hip/hip_runtime.h>
#include <hip/hip_bf16.h>

// Relative-position causal attention, B=4 H=16 Q=K=1024 D=64 (fp32 in/out).
// d_out = [output (BH*Q*D) | p_attn (BH*Q*K)] fp32.
// K1 content scores (batched per bh) -> K2 rel + exp + normalize (per q, 2 passes,
// no max subtraction) -> K3 P@V -> K4 P@bigr_v (LDS-transposed B tiles).
// Score GEMMs use split-bf16 (hi+lo, 3 MFMAs); PV GEMMs single bf16.

#define BH 64
#define SQ 1024
#define SK 1024
#define DH 64
#define SCALE 0.125f

typedef __attribute__((ext_vector_type(4))) float f32x4;
typedef __attribute__((ext_vector_type(8))) unsigned short ushort8;
typedef __attribute__((ext_vector_type(8))) __bf16 bf16x8;

static __device__ inline unsigned short f2bf(float x) {
    unsigned u = __float_as_uint(x);
    unsigned r = u + 0x7FFFu + ((u >> 16) & 1u);
    return (unsigned short)(r >> 16);
}
static __device__ inline float bf2f(unsigned short s) {
    return __uint_as_float(((unsigned)s) << 16);
}

struct Frag2 { bf16x8 h, l; };

// Load 8 contiguous fp32, produce hi/lo bf16 split fragments.
static __device__ inline Frag2 load_split(const float* __restrict__ p) {
    float4 x0 = *reinterpret_cast<const float4*>(p);
    float4 x1 = *reinterpret_cast<const float4*>(p + 4);
    float v[8] = {x0.x, x0.y, x0.z, x0.w, x1.x, x1.y, x1.z, x1.w};
    ushort8 uh, ul;
#pragma unroll
    for (int j = 0; j < 8; ++j) {
        unsigned short h = f2bf(v[j]);
        float r = v[j] - bf2f(h);
        uh[j] = h;
        ul[j] = f2bf(r);
    }
    Frag2 f;
    f.h = __builtin_bit_cast(bf16x8, uh);
    f.l = __builtin_bit_cast(bf16x8, ul);
    return f;
}

// Load 8 contiguous fp32 as single bf16 fragment.
static __device__ inline bf16x8 load_bf8(const float* __restrict__ p) {
    float4 x0 = *reinterpret_cast<const float4*>(p);
    float4 x1 = *reinterpret_cast<const float4*>(p + 4);
    float v[8] = {x0.x, x0.y, x0.z, x0.w, x1.x, x1.y, x1.z, x1.w};
    ushort8 u;
#pragma unroll
    for (int j = 0; j < 8; ++j) u[j] = f2bf(v[j]);
    return __builtin_bit_cast(bf16x8, u);
}

// Load 8 fp32 strided by `stride` floats, single bf16 fragment.
static __device__ inline bf16x8 load_bf8_strided(const float* __restrict__ p, int stride) {
    ushort8 u;
#pragma unroll
    for (int j = 0; j < 8; ++j) u[j] = f2bf(p[(size_t)j * stride]);
    return __builtin_bit_cast(bf16x8, u);
}

#define MFMA(a, b, c) __builtin_amdgcn_mfma_f32_16x16x32_bf16((a), (b), (c), 0, 0, 0)

static __device__ inline f32x4 mfma_split(const Frag2& a, const Frag2& b, f32x4 c) {
    c = MFMA(a.h, b.h, c);
    c = MFMA(a.h, b.l, c);
    c = MFMA(a.l, b.h, c);
    return c;
}

// ---------------- K1: content scores Q@K^T * scale -> P region (zeros above diag)
__global__ __launch_bounds__(256) void k_scores(const float* __restrict__ q,
                                                const float* __restrict__ k,
                                                float* __restrict__ P) {
    const int kt = blockIdx.x, qt = blockIdx.y, bh = blockIdx.z;
    const int tid = threadIdx.x;
    const int kbase = kt * 64;
    if (kbase > qt * 64 + 63) {  // fully masked tile: zeros
        const int row = qt * 64 + (tid >> 2);
        float4 z = {0.f, 0.f, 0.f, 0.f};
        float4* dst = reinterpret_cast<float4*>(
            &P[((size_t)bh * SQ + row) * SK + kbase + (tid & 3) * 16]);
        dst[0] = z; dst[1] = z; dst[2] = z; dst[3] = z;
        return;
    }
    const int w = tid >> 6, l = tid & 63;
    const int lm = l & 15, lg = l >> 4;
    const int q0 = qt * 64 + w * 16;
    const float* qrow = q + ((size_t)bh * SQ + q0 + lm) * DH + lg * 8;
    Frag2 a0 = load_split(qrow);
    Frag2 a1 = load_split(qrow + 32);
#pragma unroll
    for (int nt = 0; nt < 4; ++nt) {
        const int kc = kbase + nt * 16 + lm;
        f32x4 acc = {0.f, 0.f, 0.f, 0.f};
        if (kbase + nt * 16 <= q0 + 15) {  // tile not fully masked for this wave
            const float* krow = k + ((size_t)bh * SK + kc) * DH + lg * 8;
            Frag2 b0 = load_split(krow);
            Frag2 b1 = load_split(krow + 32);
            acc = mfma_split(a0, b0, acc);
            acc = mfma_split(a1, b1, acc);
        }
#pragma unroll
        for (int r = 0; r < 4; ++r) {
            const int qq = q0 + lg * 4 + r;
            float v = (kc <= qq) ? acc[r] * SCALE : 0.f;
            P[((size_t)bh * SQ + qq) * SK + kc] = v;
        }
    }
}

// ---------------- K2: per-q rel MFMA + exp (no max) + normalized write, 2 passes.
// Swapped operands: A = bigr_k k-rows (M), B = query bh-cols (N).
// Output lane mapping: k = k0+nt*16+lg*4+r (contiguous quad), bh = (w&3)*16+lm.
__global__ __launch_bounds__(512) void k_rel_softmax(const float* __restrict__ query,
                                                     const float* __restrict__ bigr_k,
                                                     float* __restrict__ P) {
    __shared__ float s_sums[2][64];
    const int qpos = SQ - 1 - (int)blockIdx.x;  // big rows first
    const int tid = threadIdx.x;
    const int w = tid >> 6, l = tid & 63;
    const int lm = l & 15, lg = l >> 4;
    const int g = w >> 2;                 // wave group: tiles g, g+2, g+4, ...
    const int bh = (w & 3) * 16 + lm;     // this lane's bh (N col)
    const int KE = qpos + 1;

    const float* qrow = query + ((size_t)bh * SQ + qpos) * DH + lg * 8;
    Frag2 b0 = load_split(qrow);
    Frag2 b1 = load_split(qrow + 32);

    const float* bk_base = bigr_k + (size_t)qpos * SK * DH;
    float* prow = P + ((size_t)bh * SQ + qpos) * SK;

    // pass 1: sum of exp per bh-row
    float lsum = 0.f;
    for (int t = g; t * 64 < KE; t += 2) {
        const int k0 = t * 64;
#pragma unroll
        for (int nt = 0; nt < 4; ++nt) {
            if (k0 + nt * 16 >= KE) break;
            const int kc = k0 + nt * 16 + lm;  // A row (k)
            const float* arow = bk_base + (size_t)kc * DH + lg * 8;
            Frag2 a0 = load_split(arow);
            Frag2 a1 = load_split(arow + 32);
            f32x4 acc = {0.f, 0.f, 0.f, 0.f};
            acc = mfma_split(a0, b0, acc);
            acc = mfma_split(a1, b1, acc);
            const int kq = k0 + nt * 16 + lg * 4;  // lane's k quad
            float4 c = *reinterpret_cast<const float4*>(prow + kq);
            float cv[4] = {c.x, c.y, c.z, c.w};
#pragma unroll
            for (int r = 0; r < 4; ++r)
                if (kq + r < KE) lsum += __expf(cv[r] + acc[r] * SCALE);
        }
    }
    lsum += __shfl_xor(lsum, 16);
    lsum += __shfl_xor(lsum, 32);
    if (l < 16) s_sums[g][(w & 3) * 16 + l] = lsum;
    __syncthreads();
    const float recip = 1.0f / (s_sums[0][bh] + s_sums[1][bh]);

    // pass 2: recompute and write normalized e (float4)
    for (int t = g; t * 64 < KE; t += 2) {
        const int k0 = t * 64;
#pragma unroll
        for (int nt = 0; nt < 4; ++nt) {
            if (k0 + nt * 16 >= KE) break;
            const int kc = k0 + nt * 16 + lm;
            const float* arow = bk_base + (size_t)kc * DH + lg * 8;
            Frag2 a0 = load_split(arow);
            Frag2 a1 = load_split(arow + 32);
            f32x4 acc = {0.f, 0.f, 0.f, 0.f};
            acc = mfma_split(a0, b0, acc);
            acc = mfma_split(a1, b1, acc);
            const int kq = k0 + nt * 16 + lg * 4;
            float4 c = *reinterpret_cast<const float4*>(prow + kq);
            float cv[4] = {c.x, c.y, c.z, c.w};
            float ov[4];
#pragma unroll
            for (int r = 0; r < 4; ++r)
                ov[r] = (kq + r < KE) ? __expf(cv[r] + acc[r] * SCALE) * recip : 0.f;
            float4 o;
            o.x = ov[0]; o.y = ov[1]; o.z = ov[2]; o.w = ov[3];
            *reinterpret_cast<float4*>(prow + kq) = o;
        }
    }
}

// ---------------- K3: out = P @ V (per bh, q-tiles of 64)
__global__ __launch_bounds__(256) void k_pv(const float* __restrict__ P,
                                            const float* __restrict__ V,
                                            float* __restrict__ out) {
    const int qt = blockIdx.x, bh = blockIdx.y;
    const int tid = threadIdx.x;
    const int w = tid >> 6, l = tid & 63;
    const int lm = l & 15, lg = l >> 4;
    const int q0 = qt * 64 + w * 16;
    f32x4 acc[4] = {{0.f,0.f,0.f,0.f},{0.f,0.f,0.f,0.f},{0.f,0.f,0.f,0.f},{0.f,0.f,0.f,0.f}};
    const int kend = q0 + 16;  // covers k <= q0+15; P has zeros beyond row's q
    for (int k0 = 0; k0 < kend; k0 += 32) {
        const float* arow = P + ((size_t)bh * SQ + q0 + lm) * SK + k0 + lg * 8;
        bf16x8 a = load_bf8(arow);
#pragma unroll
        for (int nt = 0; nt < 4; ++nt) {
            const float* bcol = V + ((size_t)bh * SK + k0 + lg * 8) * DH + nt * 16 + lm;
            bf16x8 b = load_bf8_strided(bcol, DH);
            acc[nt] = MFMA(a, b, acc[nt]);
        }
    }
#pragma unroll
    for (int nt = 0; nt < 4; ++nt)
#pragma unroll
        for (int r = 0; r < 4; ++r)
            out[((size_t)bh * SQ + q0 + lg * 4 + r) * DH + nt * 16 + lm] = acc[nt][r];
}

// ---------------- K4: out += P @ bigr_v[q] (per q, all bh); B staged via LDS transpose
__global__ __launch_bounds__(256) void k_pr(const float* __restrict__ P,
                                            const float* __restrict__ bigr_v,
                                            float* __restrict__ out) {
    __shared__ float vt[64][36];  // [d][k] transposed tile, padded row (36 floats)
    const int qpos = SQ - 1 - (int)blockIdx.x;  // big blocks first
    const int tid = threadIdx.x;
    const int w = tid >> 6, l = tid & 63;
    const int lm = l & 15, lg = l >> 4;
    const int bh0 = w * 16;
    const int skk = tid & 31, sdd = (tid >> 5) * 8;  // staging assignment
    f32x4 acc[4] = {{0.f,0.f,0.f,0.f},{0.f,0.f,0.f,0.f},{0.f,0.f,0.f,0.f},{0.f,0.f,0.f,0.f}};
    const int kend = qpos + 1;
    for (int k0 = 0; k0 < kend; k0 += 32) {
        __syncthreads();
        {   // stage bigr_v[qpos][k0+skk][sdd..sdd+7] -> vt[d][k] (transpose)
            const float* src = bigr_v + ((size_t)qpos * SK + k0 + skk) * DH + sdd;
            float4 v0 = *reinterpret_cast<const float4*>(src);
            float4 v1 = *reinterpret_cast<const float4*>(src + 4);
            vt[sdd + 0][skk] = v0.x; vt[sdd + 1][skk] = v0.y;
            vt[sdd + 2][skk] = v0.z; vt[sdd + 3][skk] = v0.w;
            vt[sdd + 4][skk] = v1.x; vt[sdd + 5][skk] = v1.y;
            vt[sdd + 6][skk] = v1.z; vt[sdd + 7][skk] = v1.w;
        }
        __syncthreads();
        const float* arow = P + ((size_t)(bh0 + lm) * SQ + qpos) * SK + k0 + lg * 8;
        bf16x8 a = load_bf8(arow);
#pragma unroll
        for (int nt = 0; nt < 4; ++nt) {
            const float* bp = &vt[nt * 16 + lm][lg * 8];
            float4 u0 = *reinterpret_cast<const float4*>(bp);
            float4 u1 = *reinterpret_cast<const float4*>(bp + 4);
            float bv[8] = {u0.x, u0.y, u0.z, u0.w, u1.x, u1.y, u1.z, u1.w};
            ushort8 ub;
#pragma unroll
            for (int j = 0; j < 8; ++j) ub[j] = f2bf(bv[j]);
            bf16x8 b = __builtin_bit_cast(bf16x8, ub);
            acc[nt] = MFMA(a, b, acc[nt]);
        }
    }
#pragma unroll
    for (int nt = 0; nt < 4; ++nt)
#pragma unroll
        for (int r = 0; r < 4; ++r) {
            const size_t o = ((size_t)(bh0 + lg * 4 + r) * SQ + qpos) * DH + nt * 16 + lm;
            out[o] += acc[nt][r];
        }
}

extern "C" void kernel_launch(void* const* d_in, const int* in_sizes, int n_in,
                              void* d_out, int out_size, void* d_ws, size_t ws_size,
                              hipStream_t stream) {
    const float* query  = (const float*)d_in[0];
    const float* key    = (const float*)d_in[1];
    const float* value  = (const float*)d_in[2];
    const float* bigr_k = (const float*)d_in[3];
    const float* bigr_v = (const float*)d_in[4];
    float* out = (float*)d_out;                       // BH*SQ*DH
    float* P   = out + (size_t)BH * SQ * DH;          // BH*SQ*SK

    k_scores<<<dim3(16, 16, BH), 256, 0, stream>>>(query, key, P);
    k_rel_softmax<<<dim3(SQ), 512, 0, stream>>>(query, bigr_k, P);
    k_pv<<<dim3(16, BH), 256, 0, stream>>>(P, value, out);
    k_pr<<<dim3(SQ), 256, 0, stream>>>(P, bigr_v, out);
}